// Round 6
// baseline (1761.303 us; speedup 1.0000x reference)
//
#include <hip/hip_runtime.h>
#include <hip/hip_bf16.h>
#include <stdint.h>

#define NN 100000
#define EE 1600000
#define DD 128
#define EPSV 1e-5f
#define WWIN 128                 // nodes per aggregation window (64 KB LDS fp32)
#define NB 782                   // ceil(NN / WWIN)
#define NCLS 8                   // virtual-XCD classes
#define NSEG (NCLS * NB)         // 6256 arena segments
#define ITEMS (EE / 4)           // int4 items = 400000
#define ITEMS_PER_CLS (ITEMS / NCLS) // 50000

typedef __attribute__((ext_vector_type(8))) short short8;
typedef __attribute__((ext_vector_type(4))) float floatx4;
typedef unsigned short u16;

union S8 { short8 v; short s[8]; unsigned short u[8]; };

__device__ __forceinline__ float bf2f(u16 u) {
    return __uint_as_float(((unsigned int)u) << 16);
}
__device__ __forceinline__ u16 f2bf(float f) {
    unsigned int x = __float_as_uint(f);
    x += 0x7FFFu + ((x >> 16) & 1u);
    return (u16)(x >> 16);
}

// ---------------------------------------------------------------------------
// ws layout (bytes):
//   aggb     bf16 [NN*DD]   @ 0           (25,600,000)
//   t        bf16 [NN*DD]   @ 25,600,000  (25,600,000)
//   feats_c  bf16 [NN*DD]   @ 51,200,000  (25,600,000)  (only if fp32 inputs)
//   pc       bf16 [33408]   @ 76,800,000  (66,816)
//   stats    fp32 [5*DD]    @ 76,866,816  (2,560)
//   flag     int32          @ 76,869,376  (4)
//   cnt      int [NSEG]     @ 76,869,632  (25,024)
//   off      int [NSEG+1]   @ 76,894,848  (25,028)
//   cursor   int [NSEG]     @ 76,920,064  (25,024)
//   arena    u32 [EE]       @ 76,945,408  (6,400,000)   packed (dl<<17 | src)
// pc offsets (elem): Wg 0, Wr 16384, bg 32768, br 32896, g1 33024,
//                    g2 33152, be2 33280
// ---------------------------------------------------------------------------

// ------------- dtype detection: fp32 vs bf16 --------------------------------
__global__ void k_detect(const float* __restrict__ f, int* __restrict__ flag) {
    __shared__ int cnt;
    if (threadIdx.x == 0) cnt = 0;
    __syncthreads();
    const float v = fabsf(f[threadIdx.x]);
    if (v > 1e-3f && v < 1e3f) atomicAdd(&cnt, 1);
    __syncthreads();
    if (threadIdx.x == 0) *flag = (cnt >= 128) ? 1 : 0;
}

// ------------- fp32 -> bf16 canonicalization (no-op for bf16 inputs) --------
__global__ __launch_bounds__(256) void k_convert_feats(
    const int* __restrict__ flag, const float* __restrict__ ff,
    u16* __restrict__ fc)
{
    if (*flag == 0) return;
    const size_t P = (size_t)NN * (DD / 2);
    for (size_t i = (size_t)blockIdx.x * blockDim.x + threadIdx.x; i < P;
         i += (size_t)gridDim.x * blockDim.x) {
        const float2 v = *(const float2*)(ff + 2 * i);
        const unsigned int o = (unsigned int)f2bf(v.x) | ((unsigned int)f2bf(v.y) << 16);
        *(unsigned int*)(fc + 2 * i) = o;
    }
}

__global__ __launch_bounds__(256) void k_convert_params(
    const int* __restrict__ flag,
    const float* __restrict__ Wg, const float* __restrict__ Wr,
    const float* __restrict__ bg, const float* __restrict__ br,
    const float* __restrict__ g1, const float* __restrict__ g2,
    const float* __restrict__ be2, u16* __restrict__ pc)
{
    if (*flag == 0) return;
    const int i = blockIdx.x * blockDim.x + threadIdx.x;
    if (i >= 33408) return;
    float v;
    if (i < 16384)      v = Wg[i];
    else if (i < 32768) v = Wr[i - 16384];
    else {
        const int j = i - 32768;
        const int a = j >> 7, o = j & 127;
        v = (a == 0) ? bg[o] : (a == 1) ? br[o] : (a == 2) ? g1[o]
          : (a == 3) ? g2[o] : be2[o];
    }
    pc[i] = f2bf(v);
}

// ---------------- Two-level binning ----------------------------------------
// Class (virtual XCD) of an edge = which eighth of the edge list it's in —
// a pure function of edge index, so hist and bin agree, each class's blocks
// read only their 1/8 slice (no re-scan), and each class appends to only
// its own 782 sequential arena streams (~100 KB of active lines -> lines
// fill before eviction; kills round-5's 72 MB partial-line writeback).

__global__ __launch_bounds__(256) void k_hist2(
    const int* __restrict__ dst, int* __restrict__ cnt)
{
    const int cls   = blockIdx.x & 7;
    const int blk   = blockIdx.x >> 3;
    const int nblk  = gridDim.x >> 3;
    const int it0   = cls * ITEMS_PER_CLS;
    const int it1   = it0 + ITEMS_PER_CLS;
    const int4* __restrict__ dst4 = (const int4*)dst;
    int* __restrict__ c = cnt + cls * NB;
    for (int it = it0 + blk * blockDim.x + threadIdx.x; it < it1;
         it += nblk * blockDim.x) {
        const int4 d = dst4[it];
        atomicAdd(&c[d.x >> 7], 1);
        atomicAdd(&c[d.y >> 7], 1);
        atomicAdd(&c[d.z >> 7], 1);
        atomicAdd(&c[d.w >> 7], 1);
    }
}

// single-block chunked exclusive scan of cnt[NSEG] -> off (+ cursor, sentinel)
__global__ __launch_bounds__(1024) void k_scanseg(
    const int* __restrict__ cnt, int* __restrict__ off,
    int* __restrict__ cursor)
{
    const int tx = threadIdx.x;
    const int lane = tx & 63, w = tx >> 6;
    __shared__ int wsum[16];
    __shared__ int carry;
    if (tx == 0) carry = 0;
    __syncthreads();
    for (int base = 0; base < NSEG; base += 1024) {
        const int i = base + tx;
        const int v = (i < NSEG) ? cnt[i] : 0;
        int incl = v;
#pragma unroll
        for (int d = 1; d < 64; d <<= 1) {
            const int n = __shfl_up(incl, d, 64);
            if (lane >= d) incl += n;
        }
        if (lane == 63) wsum[w] = incl;
        __syncthreads();
        if (tx < 16) {
            int s = wsum[tx];
#pragma unroll
            for (int d = 1; d < 16; d <<= 1) {
                const int n = __shfl_up(s, d, 16);
                if ((tx & 15) >= d) s += n;
            }
            wsum[tx] = s;
        }
        __syncthreads();
        const int c = carry;
        const int woff = (w == 0) ? 0 : wsum[w - 1];
        if (i < NSEG) {
            const int excl = c + woff + incl - v;
            off[i] = excl;
            cursor[i] = excl;
        }
        __syncthreads();
        if (tx == 0) carry = c + wsum[15];
        __syncthreads();
    }
    if (tx == 0) off[NSEG] = carry;   // == EE
}

__global__ __launch_bounds__(256) void k_bin(
    const int* __restrict__ src, const int* __restrict__ dst,
    int* __restrict__ cursor, unsigned int* __restrict__ arena)
{
    const int cls   = blockIdx.x & 7;
    const int blk   = blockIdx.x >> 3;
    const int nblk  = gridDim.x >> 3;
    const int it0   = cls * ITEMS_PER_CLS;
    const int it1   = it0 + ITEMS_PER_CLS;
    const int4* __restrict__ dst4 = (const int4*)dst;
    const int4* __restrict__ src4 = (const int4*)src;
    int* __restrict__ cur = cursor + cls * NB;
    for (int it = it0 + blk * blockDim.x + threadIdx.x; it < it1;
         it += nblk * blockDim.x) {
        const int4 d = dst4[it];
        const int4 s = src4[it];
        arena[atomicAdd(&cur[d.x >> 7], 1)] = ((unsigned int)(d.x & 127) << 17) | (unsigned int)s.x;
        arena[atomicAdd(&cur[d.y >> 7], 1)] = ((unsigned int)(d.y & 127) << 17) | (unsigned int)s.y;
        arena[atomicAdd(&cur[d.z >> 7], 1)] = ((unsigned int)(d.z & 127) << 17) | (unsigned int)s.z;
        arena[atomicAdd(&cur[d.w >> 7], 1)] = ((unsigned int)(d.w & 127) << 17) | (unsigned int)s.w;
    }
}

// ---------------- Window aggregation: LDS fp32 accumulator ------------------
// one block per 128-node window; lane owns cols {2l, 2l+1}; per edge the
// wave gathers the full 256 B feats row and ds_add_f32's into sacc[dl][*].
__global__ __launch_bounds__(256) void k_winagg(
    const int* __restrict__ flag,
    const u16* __restrict__ feats_raw, const u16* __restrict__ feats_c,
    const unsigned int* __restrict__ arena, const int* __restrict__ off,
    u16* __restrict__ aggb)
{
    const u16* __restrict__ F = (*flag != 0) ? feats_c : feats_raw;
    __shared__ float sacc[WWIN][DD];   // 64 KB
    const int tx = threadIdx.x;
    const int lane = tx & 63;
    const int wv = tx >> 6;
    const int b = blockIdx.x;          // window id

    float4* z = (float4*)&sacc[0][0];
    for (int i = tx; i < WWIN * DD / 4; i += 256) z[i] = make_float4(0.f, 0.f, 0.f, 0.f);
    __syncthreads();

#pragma unroll 1
    for (int v = 0; v < NCLS; ++v) {
        const int i0 = v * NB + b;
        const int st = off[i0];
        const int len = off[i0 + 1] - st;
        for (int base = wv * 64; base < len; base += 256) {
            const int nb = (len - base) < 64 ? (len - base) : 64;
            unsigned int p = 0;
            if (lane < nb) p = arena[st + base + lane];
            int j = 0;
            for (; j + 8 <= nb; j += 8) {
                unsigned int pp[8], vv[8];
#pragma unroll
                for (int q = 0; q < 8; ++q) {
                    pp[q] = (unsigned int)__shfl((int)p, j + q, 64);
                    const int s = (int)(pp[q] & 0x1FFFFu);
                    vv[q] = *(const unsigned int*)(F + (size_t)s * DD + lane * 2);
                }
#pragma unroll
                for (int q = 0; q < 8; ++q) {
                    const int dl = (int)(pp[q] >> 17);
                    atomicAdd(&sacc[dl][2 * lane],     bf2f((u16)(vv[q] & 0xFFFFu)));
                    atomicAdd(&sacc[dl][2 * lane + 1], bf2f((u16)(vv[q] >> 16)));
                }
            }
            for (; j < nb; ++j) {
                const unsigned int pj = (unsigned int)__shfl((int)p, j, 64);
                const int s = (int)(pj & 0x1FFFFu);
                const int dl = (int)(pj >> 17);
                const unsigned int v0 = *(const unsigned int*)(F + (size_t)s * DD + lane * 2);
                atomicAdd(&sacc[dl][2 * lane],     bf2f((u16)(v0 & 0xFFFFu)));
                atomicAdd(&sacc[dl][2 * lane + 1], bf2f((u16)(v0 >> 16)));
            }
        }
    }
    __syncthreads();

    // epilogue: write bf16 aggb rows (lane-contiguous 256 B per row)
    for (int i = tx; i < WWIN * 64; i += 256) {
        const int row = i >> 6;
        const int cp  = i & 63;
        const int node = b * WWIN + row;
        if (node < NN) {
            const float f0 = sacc[row][2 * cp];
            const float f1 = sacc[row][2 * cp + 1];
            const unsigned int o = (unsigned int)f2bf(f0) | ((unsigned int)f2bf(f1) << 16);
            *(unsigned int*)(aggb + (size_t)node * DD + 2 * cp) = o;
        }
    }
}

// ---------------- Kernel B: fused dual GEMM + relu + add --------------------
__global__ __launch_bounds__(256) void k_gemm(
    const int* __restrict__ flag,
    const u16* __restrict__ aggb,
    const u16* __restrict__ feats_raw, const u16* __restrict__ feats_c,
    const u16* __restrict__ Wg_raw, const u16* __restrict__ bg_raw,
    const u16* __restrict__ Wr_raw, const u16* __restrict__ br_raw,
    const u16* __restrict__ pc,
    u16* __restrict__ t_out)
{
    const bool f32 = (*flag != 0);
    const u16* __restrict__ F  = f32 ? feats_c     : feats_raw;
    const u16* __restrict__ Wg = f32 ? pc          : Wg_raw;
    const u16* __restrict__ Wr = f32 ? pc + 16384  : Wr_raw;
    const u16* __restrict__ bg = f32 ? pc + 32768  : bg_raw;
    const u16* __restrict__ br = f32 ? pc + 32896  : br_raw;

    const int lane = threadIdx.x & 63;
    const int wv   = threadIdx.x >> 6;
    const int l15  = lane & 15;
    const int quad = lane >> 4;
    const int c0 = wv * 16 + l15;
    const int c1 = 64 + wv * 16 + l15;

    S8 fg0[4], fg1[4], fr0[4], fr1[4];
#pragma unroll
    for (int kb = 0; kb < 4; ++kb) {
        const int kr = kb * 32 + quad * 8;
#pragma unroll
        for (int j = 0; j < 8; ++j) {
            fg0[kb].u[j] = Wg[(size_t)(kr + j) * DD + c0];
            fg1[kb].u[j] = Wg[(size_t)(kr + j) * DD + c1];
            fr0[kb].u[j] = Wr[(size_t)(kr + j) * DD + c0];
            fr1[kb].u[j] = Wr[(size_t)(kr + j) * DD + c1];
        }
    }
    const float bgc0 = bf2f(bg[c0]), bgc1 = bf2f(bg[c1]);
    const float brc0 = bf2f(br[c0]), brc1 = bf2f(br[c1]);

    for (int tile = blockIdx.x; tile < NN / 16; tile += gridDim.x) {
        const int row0 = tile * 16;
        const int arow = row0 + l15;
        floatx4 ag0 = {0.f,0.f,0.f,0.f}, ag1 = {0.f,0.f,0.f,0.f};
        floatx4 ar0 = {0.f,0.f,0.f,0.f}, ar1 = {0.f,0.f,0.f,0.f};
#pragma unroll
        for (int kb = 0; kb < 4; ++kb) {
            const int kbase = kb * 32 + quad * 8;
            S8 av, ff;
            av.v = *(const short8*)(aggb + (size_t)arow * DD + kbase);
            ff.v = *(const short8*)(F    + (size_t)arow * DD + kbase);
            ag0 = __builtin_amdgcn_mfma_f32_16x16x32_bf16(av.v, fg0[kb].v, ag0, 0, 0, 0);
            ag1 = __builtin_amdgcn_mfma_f32_16x16x32_bf16(av.v, fg1[kb].v, ag1, 0, 0, 0);
            ar0 = __builtin_amdgcn_mfma_f32_16x16x32_bf16(ff.v, fr0[kb].v, ar0, 0, 0, 0);
            ar1 = __builtin_amdgcn_mfma_f32_16x16x32_bf16(ff.v, fr1[kb].v, ar1, 0, 0, 0);
        }
#pragma unroll
        for (int r = 0; r < 4; ++r) {
            const int row = row0 + quad * 4 + r;
            const float t0 = fmaxf(ag0[r] + bgc0, 0.f) + fmaxf(ar0[r] + brc0, 0.f);
            const float t1 = fmaxf(ag1[r] + bgc1, 0.f) + fmaxf(ar1[r] + brc1, 0.f);
            t_out[(size_t)row * DD + c0] = f2bf(t0);
            t_out[(size_t)row * DD + c1] = f2bf(t1);
        }
    }
}

// ---------------- Kernel C: column stats ------------------------------------
__global__ __launch_bounds__(256) void k_stats(
    const int* __restrict__ flag,
    const u16* __restrict__ t,
    const u16* __restrict__ feats_raw, const u16* __restrict__ feats_c,
    float* __restrict__ stats)
{
    const u16* __restrict__ F = (*flag != 0) ? feats_c : feats_raw;
    const int tx = threadIdx.x;
    const int c2 = (tx & 63) * 2;
    const int rg = tx >> 6;
    float acc[10];
#pragma unroll
    for (int k = 0; k < 10; ++k) acc[k] = 0.f;

    for (int r = blockIdx.x * 4 + rg; r < NN; r += gridDim.x * 4) {
        const unsigned int tv = *(const unsigned int*)(t + (size_t)r * DD + c2);
        const unsigned int fv = *(const unsigned int*)(F + (size_t)r * DD + c2);
        const float t0 = bf2f((u16)(tv & 0xFFFFu));
        const float t1 = bf2f((u16)(tv >> 16));
        const float f0 = bf2f((u16)(fv & 0xFFFFu));
        const float f1 = bf2f((u16)(fv >> 16));
        acc[0] += t0;      acc[1] += t1;
        acc[2] += t0 * t0; acc[3] += t1 * t1;
        acc[4] += f0;      acc[5] += f1;
        acc[6] += f0 * f0; acc[7] += f1 * f1;
        acc[8] += t0 * f0; acc[9] += t1 * f1;
    }

    __shared__ float red[256][10];
#pragma unroll
    for (int k = 0; k < 10; ++k) red[tx][k] = acc[k];
    __syncthreads();
    if (tx < 64) {
#pragma unroll
        for (int k = 0; k < 10; ++k) {
            const float v = red[tx][k] + red[tx + 64][k] + red[tx + 128][k] + red[tx + 192][k];
            unsafeAtomicAdd(&stats[(k >> 1) * DD + c2 + (k & 1)], v);
        }
    }
}

// ---------------- Kernel D: fused BN1+residual+BN2 elementwise --------------
__global__ __launch_bounds__(256) void k_final(
    const int* __restrict__ flag,
    const u16* __restrict__ t,
    const u16* __restrict__ feats_raw, const u16* __restrict__ feats_c,
    const u16* __restrict__ g1_raw, const u16* __restrict__ g2_raw,
    const u16* __restrict__ be2_raw, const u16* __restrict__ pc,
    const float* __restrict__ stats,
    void* __restrict__ out)
{
    const bool f32 = (*flag != 0);
    const u16* __restrict__ F   = f32 ? feats_c    : feats_raw;
    const u16* __restrict__ g1  = f32 ? pc + 33024 : g1_raw;
    const u16* __restrict__ g2  = f32 ? pc + 33152 : g2_raw;
    const u16* __restrict__ be2 = f32 ? pc + 33280 : be2_raw;

    __shared__ float sA[DD], sB[DD], sG[DD];
    if (threadIdx.x < DD) {
        const int c = threadIdx.x;
        const float invN = 1.0f / (float)NN;
        const float St  = stats[c],          Stt = stats[DD + c];
        const float Sf  = stats[2 * DD + c], Sff = stats[3 * DD + c];
        const float Stf = stats[4 * DD + c];
        const float mu1  = St * invN;
        const float vart = fmaxf(Stt * invN - mu1 * mu1, 0.f);
        const float muf  = Sf * invN;
        const float varf = fmaxf(Sff * invN - muf * muf, 0.f);
        const float cov  = Stf * invN - mu1 * muf;
        const float r1   = rsqrtf(vart + EPSV);
        const float a1   = bf2f(g1[c]) * r1;
        const float var2 = fmaxf(a1 * a1 * vart + 2.f * a1 * cov + varf, 0.f);
        const float r2   = rsqrtf(var2 + EPSV);
        const float g2r2 = bf2f(g2[c]) * r2;
        sA[c] = g2r2 * a1;
        sB[c] = g2r2;
        sG[c] = bf2f(be2[c]) - g2r2 * (a1 * mu1 + muf);
    }
    __syncthreads();

    float* outf = (float*)out;
    u16*   outb = (u16*)out;
    const size_t P = (size_t)NN * (DD / 2);
    for (size_t i = (size_t)blockIdx.x * blockDim.x + threadIdx.x; i < P;
         i += (size_t)gridDim.x * blockDim.x) {
        const int c = ((int)(i & 63)) * 2;
        const unsigned int tv = *(const unsigned int*)(t + 2 * i);
        const unsigned int fv = *(const unsigned int*)(F + 2 * i);
        const float o0 = sA[c]     * bf2f((u16)(tv & 0xFFFFu))
                       + sB[c]     * bf2f((u16)(fv & 0xFFFFu)) + sG[c];
        const float o1 = sA[c + 1] * bf2f((u16)(tv >> 16))
                       + sB[c + 1] * bf2f((u16)(fv >> 16)) + sG[c + 1];
        if (f32) {
            float2 o; o.x = o0; o.y = o1;
            *(float2*)(outf + 2 * i) = o;
        } else {
            const unsigned int ov = (unsigned int)f2bf(o0) | ((unsigned int)f2bf(o1) << 16);
            *(unsigned int*)(outb + 2 * i) = ov;
        }
    }
}

extern "C" void kernel_launch(void* const* d_in, const int* in_sizes, int n_in,
                              void* d_out, int out_size, void* d_ws, size_t ws_size,
                              hipStream_t stream) {
    const u16* feats = (const u16*)d_in[0];
    const u16* Wg    = (const u16*)d_in[1];
    const u16* bg    = (const u16*)d_in[2];
    const u16* Wr    = (const u16*)d_in[3];
    const u16* br    = (const u16*)d_in[4];
    const u16* g1    = (const u16*)d_in[5];
    // d_in[6] = be1: cancels algebraically, unused
    const u16* g2    = (const u16*)d_in[7];
    const u16* be2   = (const u16*)d_in[8];
    const int* src = (const int*)d_in[9];
    const int* dst = (const int*)d_in[10];

    char* ws = (char*)d_ws;
    u16*          aggb    = (u16*)  ws;
    u16*          t       = (u16*)  (ws + 25600000);
    u16*          feats_c = (u16*)  (ws + 51200000);
    u16*          pc      = (u16*)  (ws + 76800000);
    float*        stats   = (float*)(ws + 76866816);
    int*          flag    = (int*)  (ws + 76869376);
    int*          cnt     = (int*)  (ws + 76869632);
    int*          off     = (int*)  (ws + 76894848);
    int*          cursor  = (int*)  (ws + 76920064);
    unsigned int* arena   = (unsigned int*)(ws + 76945408);

    hipMemsetAsync(cnt,   0, NSEG * sizeof(int), stream);
    hipMemsetAsync(stats, 0, 5 * DD * sizeof(float), stream);

    k_detect<<<1, 256, 0, stream>>>((const float*)d_in[0], flag);
    k_convert_feats<<<1024, 256, 0, stream>>>(flag, (const float*)d_in[0], feats_c);
    k_convert_params<<<131, 256, 0, stream>>>(flag,
        (const float*)d_in[1], (const float*)d_in[3], (const float*)d_in[2],
        (const float*)d_in[4], (const float*)d_in[5], (const float*)d_in[7],
        (const float*)d_in[8], pc);

    k_hist2  <<<1024, 256, 0, stream>>>(dst, cnt);
    k_scanseg<<<1, 1024, 0, stream>>>(cnt, off, cursor);
    k_bin    <<<1024, 256, 0, stream>>>(src, dst, cursor, arena);
    k_winagg <<<NB, 256, 0, stream>>>(flag, feats, feats_c, arena, off, aggb);

    k_gemm  <<<1024, 256, 0, stream>>>(flag, aggb, feats, feats_c, Wg, bg, Wr, br, pc, t);
    k_stats <<<400,  256, 0, stream>>>(flag, t, feats, feats_c, stats);
    k_final <<<2048, 256, 0, stream>>>(flag, t, feats, feats_c, g1, g2, be2, pc, stats, d_out);
}

// Round 7
// 343.828 us; speedup vs baseline: 5.1226x; 5.1226x over previous
//
#include <hip/hip_runtime.h>
#include <hip/hip_bf16.h>
#include <stdint.h>

#define NN 100000
#define EE 1600000
#define DD 128
#define EPSV 1e-5f
#define WWIN 128                 // nodes per window
#define NB 782                   // ceil(NN / WWIN)
#define NCLS 8                   // edge-list slices (hist/bin agree by construction)
#define NSEG (NB * NCLS)         // 6256 segments, WINDOW-major: seg = win*8+cls
#define ITEMS (EE / 4)           // 400000 int4 items
#define ITEMS_PER_CLS (ITEMS / NCLS) // 50000
#define SORTCAP 4096             // winsort LDS stash (mean len 2046, sd ~45)

typedef __attribute__((ext_vector_type(8))) short short8;
typedef __attribute__((ext_vector_type(4))) float floatx4;
typedef unsigned short u16;

union S8 { short8 v; short s[8]; unsigned short u[8]; };

__device__ __forceinline__ float bf2f(u16 u) {
    return __uint_as_float(((unsigned int)u) << 16);
}
__device__ __forceinline__ u16 f2bf(float f) {
    unsigned int x = __float_as_uint(f);
    x += 0x7FFFu + ((x >> 16) & 1u);
    return (u16)(x >> 16);
}

// ---------------------------------------------------------------------------
// ws layout (bytes):
//   aggb     bf16 [NN*DD]   @ 0           (25,600,000)
//   t        bf16 [NN*DD]   @ 25,600,000  (25,600,000)
//   feats_c  bf16 [NN*DD]   @ 51,200,000  (25,600,000)  (only if fp32 inputs)
//   pc       bf16 [33408]   @ 76,800,000  (66,816)
//   stats    fp32 [5*DD]    @ 76,866,816  (2,560)
//   flag     int32          @ 76,869,376  (4 + pad)
//   cnt      int [NSEG]     @ 76,869,632  (25,024)
//   off      int [NSEG+1]   @ 76,894,656  (25,028)
//   cursor   int [NSEG]     @ 76,919,684  (25,024)
//   row_st   int [NN+1]     @ 76,944,708  (400,004)
//   arena    u32 [EE]       @ 77,344,712  (6,400,000)  -> ends 83,744,712
// arena: pass 1 packed (dl<<17|src); after k_winsort: per-node-sorted src ints
// ---------------------------------------------------------------------------

// ------------- dtype detection: fp32 vs bf16 --------------------------------
__global__ void k_detect(const float* __restrict__ f, int* __restrict__ flag) {
    __shared__ int cnt;
    if (threadIdx.x == 0) cnt = 0;
    __syncthreads();
    const float v = fabsf(f[threadIdx.x]);
    if (v > 1e-3f && v < 1e3f) atomicAdd(&cnt, 1);
    __syncthreads();
    if (threadIdx.x == 0) *flag = (cnt >= 128) ? 1 : 0;
}

// ------------- fp32 -> bf16 canonicalization (no-op for bf16 inputs) --------
__global__ __launch_bounds__(256) void k_convert_feats(
    const int* __restrict__ flag, const float* __restrict__ ff,
    u16* __restrict__ fc)
{
    if (*flag == 0) return;
    const size_t P = (size_t)NN * (DD / 2);
    for (size_t i = (size_t)blockIdx.x * blockDim.x + threadIdx.x; i < P;
         i += (size_t)gridDim.x * blockDim.x) {
        const float2 v = *(const float2*)(ff + 2 * i);
        const unsigned int o = (unsigned int)f2bf(v.x) | ((unsigned int)f2bf(v.y) << 16);
        *(unsigned int*)(fc + 2 * i) = o;
    }
}

__global__ __launch_bounds__(256) void k_convert_params(
    const int* __restrict__ flag,
    const float* __restrict__ Wg, const float* __restrict__ Wr,
    const float* __restrict__ bg, const float* __restrict__ br,
    const float* __restrict__ g1, const float* __restrict__ g2,
    const float* __restrict__ be2, u16* __restrict__ pc)
{
    if (*flag == 0) return;
    const int i = blockIdx.x * blockDim.x + threadIdx.x;
    if (i >= 33408) return;
    float v;
    if (i < 16384)      v = Wg[i];
    else if (i < 32768) v = Wr[i - 16384];
    else {
        const int j = i - 32768;
        const int a = j >> 7, o = j & 127;
        v = (a == 0) ? bg[o] : (a == 1) ? br[o] : (a == 2) ? g1[o]
          : (a == 3) ? g2[o] : be2[o];
    }
    pc[i] = f2bf(v);
}

// ---------------- Binning: LDS-staged histogram -----------------------------
__global__ __launch_bounds__(256) void k_hist2(
    const int* __restrict__ dst, int* __restrict__ cnt)
{
    __shared__ int lc[NB];
    const int cls  = blockIdx.x & 7;
    const int blk  = blockIdx.x >> 3;
    const int nblk = gridDim.x >> 3;
    const int it0  = cls * ITEMS_PER_CLS;
    const int it1  = it0 + ITEMS_PER_CLS;
    for (int i = threadIdx.x; i < NB; i += 256) lc[i] = 0;
    __syncthreads();
    const int4* __restrict__ dst4 = (const int4*)dst;
    for (int it = it0 + blk * blockDim.x + threadIdx.x; it < it1;
         it += nblk * blockDim.x) {
        const int4 d = dst4[it];
        atomicAdd(&lc[d.x >> 7], 1);
        atomicAdd(&lc[d.y >> 7], 1);
        atomicAdd(&lc[d.z >> 7], 1);
        atomicAdd(&lc[d.w >> 7], 1);
    }
    __syncthreads();
    for (int i = threadIdx.x; i < NB; i += 256) {
        const int v = lc[i];
        if (v) atomicAdd(&cnt[i * NCLS + cls], v);
    }
}

// single-block chunked exclusive scan of cnt[NSEG] -> off (+cursor, sentinel)
__global__ __launch_bounds__(1024) void k_scanseg(
    const int* __restrict__ cnt, int* __restrict__ off,
    int* __restrict__ cursor)
{
    const int tx = threadIdx.x;
    const int lane = tx & 63, w = tx >> 6;
    __shared__ int wsum[16];
    __shared__ int carry;
    if (tx == 0) carry = 0;
    __syncthreads();
    for (int base = 0; base < NSEG; base += 1024) {
        const int i = base + tx;
        const int v = (i < NSEG) ? cnt[i] : 0;
        int incl = v;
#pragma unroll
        for (int d = 1; d < 64; d <<= 1) {
            const int n = __shfl_up(incl, d, 64);
            if (lane >= d) incl += n;
        }
        if (lane == 63) wsum[w] = incl;
        __syncthreads();
        if (tx < 16) {
            int s = wsum[tx];
#pragma unroll
            for (int d = 1; d < 16; d <<= 1) {
                const int n = __shfl_up(s, d, 16);
                if ((tx & 15) >= d) s += n;
            }
            wsum[tx] = s;
        }
        __syncthreads();
        const int c = carry;
        const int woff = (w == 0) ? 0 : wsum[w - 1];
        if (i < NSEG) {
            const int excl = c + woff + incl - v;
            off[i] = excl;
            cursor[i] = excl;
        }
        __syncthreads();
        if (tx == 0) carry = c + wsum[15];
        __syncthreads();
    }
    if (tx == 0) off[NSEG] = carry;   // == EE
}

// two-pass LDS-staged bin: local count -> one range-reserve atomic per seg ->
// scatter packed (dl<<17|src) into arena
__global__ __launch_bounds__(256) void k_bin(
    const int* __restrict__ src, const int* __restrict__ dst,
    int* __restrict__ cursor, unsigned int* __restrict__ arena)
{
    __shared__ int lc[NB], lb[NB];
    const int cls  = blockIdx.x & 7;
    const int blk  = blockIdx.x >> 3;
    const int nblk = gridDim.x >> 3;
    const int it0  = cls * ITEMS_PER_CLS;
    const int it1  = it0 + ITEMS_PER_CLS;
    const int4* __restrict__ dst4 = (const int4*)dst;
    const int4* __restrict__ src4 = (const int4*)src;
    for (int i = threadIdx.x; i < NB; i += 256) lc[i] = 0;
    __syncthreads();
    for (int it = it0 + blk * blockDim.x + threadIdx.x; it < it1;
         it += nblk * blockDim.x) {
        const int4 d = dst4[it];
        atomicAdd(&lc[d.x >> 7], 1);
        atomicAdd(&lc[d.y >> 7], 1);
        atomicAdd(&lc[d.z >> 7], 1);
        atomicAdd(&lc[d.w >> 7], 1);
    }
    __syncthreads();
    for (int i = threadIdx.x; i < NB; i += 256) {
        const int v = lc[i];
        lb[i] = v ? atomicAdd(&cursor[i * NCLS + cls], v) : 0;
    }
    __syncthreads();
    for (int i = threadIdx.x; i < NB; i += 256) lc[i] = 0;
    __syncthreads();
    for (int it = it0 + blk * blockDim.x + threadIdx.x; it < it1;
         it += nblk * blockDim.x) {
        const int4 d = dst4[it];
        const int4 s = src4[it];
        int wv, p;
        wv = d.x >> 7; p = lb[wv] + atomicAdd(&lc[wv], 1);
        arena[p] = ((unsigned int)(d.x & 127) << 17) | (unsigned int)s.x;
        wv = d.y >> 7; p = lb[wv] + atomicAdd(&lc[wv], 1);
        arena[p] = ((unsigned int)(d.y & 127) << 17) | (unsigned int)s.y;
        wv = d.z >> 7; p = lb[wv] + atomicAdd(&lc[wv], 1);
        arena[p] = ((unsigned int)(d.z & 127) << 17) | (unsigned int)s.z;
        wv = d.w >> 7; p = lb[wv] + atomicAdd(&lc[wv], 1);
        arena[p] = ((unsigned int)(d.w & 127) << 17) | (unsigned int)s.w;
    }
}

// ---------------- Per-window counting sort (in place) -----------------------
// window b's edges are contiguous: [off[b*8], off[b*8+8]). Stash to LDS,
// count per node, scan, scatter back node-sorted (plain src ints).
// Produces global per-node CSR row_st[NN+1].
__global__ __launch_bounds__(256) void k_winsort(
    unsigned int* __restrict__ arena, const int* __restrict__ off,
    int* __restrict__ row_st)
{
    __shared__ unsigned int buf[SORTCAP];
    __shared__ int cnt[WWIN], pref[WWIN], cur[WWIN];
    const int tx = threadIdx.x;
    const int b = blockIdx.x;
    const int s0 = off[b * NCLS];
    const int s1 = off[b * NCLS + NCLS];
    int len = s1 - s0;
    if (len > SORTCAP) len = SORTCAP;   // unreachable for this input dist
    if (tx < WWIN) cnt[tx] = 0;
    __syncthreads();
    for (int i = tx; i < len; i += 256) {
        const unsigned int p = arena[s0 + i];
        buf[i] = p;
        atomicAdd(&cnt[p >> 17], 1);
    }
    __syncthreads();
    if (tx < WWIN) pref[tx] = cnt[tx];
    __syncthreads();
    for (int d = 1; d < WWIN; d <<= 1) {           // Hillis-Steele inclusive
        int v = 0;
        if (tx < WWIN && tx >= d) v = pref[tx - d];
        __syncthreads();
        if (tx < WWIN) pref[tx] += v;
        __syncthreads();
    }
    if (tx < WWIN) {
        const int excl = pref[tx] - cnt[tx];
        cur[tx] = excl;
        const int node = b * WWIN + tx;
        if (node < NN) row_st[node] = s0 + excl;
    }
    if (b == NB - 1 && tx == 0) row_st[NN] = EE;
    __syncthreads();
    for (int i = tx; i < len; i += 256) {
        const unsigned int p = buf[i];
        const int pos = atomicAdd(&cur[p >> 17], 1);
        arena[s0 + pos] = p & 0x1FFFFu;            // plain src index
    }
}

// ---------------- Gather aggregation: 2 edges per wave-instruction ----------
// half-wave h (lane>>5) processes edge slot j+h; lane&31 covers 4 cols via
// uint2 (8 B). 8-deep unroll => 16 edges in flight per drain. No LDS.
__global__ __launch_bounds__(256) void k_gather(
    const int* __restrict__ flag,
    const u16* __restrict__ feats_raw, const u16* __restrict__ feats_c,
    const int* __restrict__ edge_s, const int* __restrict__ row_st,
    u16* __restrict__ aggb)
{
    const u16* __restrict__ F = (*flag != 0) ? feats_c : feats_raw;
    const int lane = threadIdx.x & 63;
    const int half = lane >> 5;
    const int l32  = lane & 31;
    const int wave = (blockIdx.x * blockDim.x + threadIdx.x) >> 6;
    const int nw   = (gridDim.x * blockDim.x) >> 6;
    for (int node = wave; node < NN; node += nw) {
        const int rs  = row_st[node];
        const int deg = row_st[node + 1] - rs;
        float a0 = 0.f, a1 = 0.f, a2 = 0.f, a3 = 0.f;
        for (int base = 0; base < deg; base += 64) {
            const int rem = deg - base;
            const int nb  = rem < 64 ? rem : 64;
            int idx = 0;
            if (lane < nb) idx = edge_s[rs + base + lane];
            int j = 0;
            for (; j + 16 <= nb; j += 16) {
                uint2 vv[8];
#pragma unroll
                for (int q = 0; q < 8; ++q) {
                    const int s = __shfl(idx, j + 2 * q + half, 64);
                    vv[q] = *(const uint2*)(F + (size_t)s * DD + l32 * 4);
                }
#pragma unroll
                for (int q = 0; q < 8; ++q) {
                    a0 += bf2f((u16)(vv[q].x & 0xFFFFu));
                    a1 += bf2f((u16)(vv[q].x >> 16));
                    a2 += bf2f((u16)(vv[q].y & 0xFFFFu));
                    a3 += bf2f((u16)(vv[q].y >> 16));
                }
            }
            for (; j + 2 <= nb; j += 2) {
                const int s = __shfl(idx, j + half, 64);
                const uint2 v = *(const uint2*)(F + (size_t)s * DD + l32 * 4);
                a0 += bf2f((u16)(v.x & 0xFFFFu));
                a1 += bf2f((u16)(v.x >> 16));
                a2 += bf2f((u16)(v.y & 0xFFFFu));
                a3 += bf2f((u16)(v.y >> 16));
            }
            if (j < nb) {
                const int s = __shfl(idx, j, 64);
                const uint2 v = *(const uint2*)(F + (size_t)s * DD + l32 * 4);
                if (half == 0) {
                    a0 += bf2f((u16)(v.x & 0xFFFFu));
                    a1 += bf2f((u16)(v.x >> 16));
                    a2 += bf2f((u16)(v.y & 0xFFFFu));
                    a3 += bf2f((u16)(v.y >> 16));
                }
            }
        }
        a0 += __shfl_xor(a0, 32, 64);
        a1 += __shfl_xor(a1, 32, 64);
        a2 += __shfl_xor(a2, 32, 64);
        a3 += __shfl_xor(a3, 32, 64);
        if (half == 0) {
            uint2 o;
            o.x = (unsigned int)f2bf(a0) | ((unsigned int)f2bf(a1) << 16);
            o.y = (unsigned int)f2bf(a2) | ((unsigned int)f2bf(a3) << 16);
            *(uint2*)(aggb + (size_t)node * DD + l32 * 4) = o;
        }
    }
}

// ---------------- Kernel B: fused dual GEMM + relu + add --------------------
__global__ __launch_bounds__(256) void k_gemm(
    const int* __restrict__ flag,
    const u16* __restrict__ aggb,
    const u16* __restrict__ feats_raw, const u16* __restrict__ feats_c,
    const u16* __restrict__ Wg_raw, const u16* __restrict__ bg_raw,
    const u16* __restrict__ Wr_raw, const u16* __restrict__ br_raw,
    const u16* __restrict__ pc,
    u16* __restrict__ t_out)
{
    const bool f32 = (*flag != 0);
    const u16* __restrict__ F  = f32 ? feats_c     : feats_raw;
    const u16* __restrict__ Wg = f32 ? pc          : Wg_raw;
    const u16* __restrict__ Wr = f32 ? pc + 16384  : Wr_raw;
    const u16* __restrict__ bg = f32 ? pc + 32768  : bg_raw;
    const u16* __restrict__ br = f32 ? pc + 32896  : br_raw;

    const int lane = threadIdx.x & 63;
    const int wv   = threadIdx.x >> 6;
    const int l15  = lane & 15;
    const int quad = lane >> 4;
    const int c0 = wv * 16 + l15;
    const int c1 = 64 + wv * 16 + l15;

    S8 fg0[4], fg1[4], fr0[4], fr1[4];
#pragma unroll
    for (int kb = 0; kb < 4; ++kb) {
        const int kr = kb * 32 + quad * 8;
#pragma unroll
        for (int j = 0; j < 8; ++j) {
            fg0[kb].u[j] = Wg[(size_t)(kr + j) * DD + c0];
            fg1[kb].u[j] = Wg[(size_t)(kr + j) * DD + c1];
            fr0[kb].u[j] = Wr[(size_t)(kr + j) * DD + c0];
            fr1[kb].u[j] = Wr[(size_t)(kr + j) * DD + c1];
        }
    }
    const float bgc0 = bf2f(bg[c0]), bgc1 = bf2f(bg[c1]);
    const float brc0 = bf2f(br[c0]), brc1 = bf2f(br[c1]);

    for (int tile = blockIdx.x; tile < NN / 16; tile += gridDim.x) {
        const int row0 = tile * 16;
        const int arow = row0 + l15;
        floatx4 ag0 = {0.f,0.f,0.f,0.f}, ag1 = {0.f,0.f,0.f,0.f};
        floatx4 ar0 = {0.f,0.f,0.f,0.f}, ar1 = {0.f,0.f,0.f,0.f};
#pragma unroll
        for (int kb = 0; kb < 4; ++kb) {
            const int kbase = kb * 32 + quad * 8;
            S8 av, ff;
            av.v = *(const short8*)(aggb + (size_t)arow * DD + kbase);
            ff.v = *(const short8*)(F    + (size_t)arow * DD + kbase);
            ag0 = __builtin_amdgcn_mfma_f32_16x16x32_bf16(av.v, fg0[kb].v, ag0, 0, 0, 0);
            ag1 = __builtin_amdgcn_mfma_f32_16x16x32_bf16(av.v, fg1[kb].v, ag1, 0, 0, 0);
            ar0 = __builtin_amdgcn_mfma_f32_16x16x32_bf16(ff.v, fr0[kb].v, ar0, 0, 0, 0);
            ar1 = __builtin_amdgcn_mfma_f32_16x16x32_bf16(ff.v, fr1[kb].v, ar1, 0, 0, 0);
        }
#pragma unroll
        for (int r = 0; r < 4; ++r) {
            const int row = row0 + quad * 4 + r;
            const float t0 = fmaxf(ag0[r] + bgc0, 0.f) + fmaxf(ar0[r] + brc0, 0.f);
            const float t1 = fmaxf(ag1[r] + bgc1, 0.f) + fmaxf(ar1[r] + brc1, 0.f);
            t_out[(size_t)row * DD + c0] = f2bf(t0);
            t_out[(size_t)row * DD + c1] = f2bf(t1);
        }
    }
}

// ---------------- Kernel C: column stats ------------------------------------
__global__ __launch_bounds__(256) void k_stats(
    const int* __restrict__ flag,
    const u16* __restrict__ t,
    const u16* __restrict__ feats_raw, const u16* __restrict__ feats_c,
    float* __restrict__ stats)
{
    const u16* __restrict__ F = (*flag != 0) ? feats_c : feats_raw;
    const int tx = threadIdx.x;
    const int c2 = (tx & 63) * 2;
    const int rg = tx >> 6;
    float acc[10];
#pragma unroll
    for (int k = 0; k < 10; ++k) acc[k] = 0.f;

    for (int r = blockIdx.x * 4 + rg; r < NN; r += gridDim.x * 4) {
        const unsigned int tv = *(const unsigned int*)(t + (size_t)r * DD + c2);
        const unsigned int fv = *(const unsigned int*)(F + (size_t)r * DD + c2);
        const float t0 = bf2f((u16)(tv & 0xFFFFu));
        const float t1 = bf2f((u16)(tv >> 16));
        const float f0 = bf2f((u16)(fv & 0xFFFFu));
        const float f1 = bf2f((u16)(fv >> 16));
        acc[0] += t0;      acc[1] += t1;
        acc[2] += t0 * t0; acc[3] += t1 * t1;
        acc[4] += f0;      acc[5] += f1;
        acc[6] += f0 * f0; acc[7] += f1 * f1;
        acc[8] += t0 * f0; acc[9] += t1 * f1;
    }

    __shared__ float red[256][10];
#pragma unroll
    for (int k = 0; k < 10; ++k) red[tx][k] = acc[k];
    __syncthreads();
    if (tx < 64) {
#pragma unroll
        for (int k = 0; k < 10; ++k) {
            const float v = red[tx][k] + red[tx + 64][k] + red[tx + 128][k] + red[tx + 192][k];
            unsafeAtomicAdd(&stats[(k >> 1) * DD + c2 + (k & 1)], v);
        }
    }
}

// ---------------- Kernel D: fused BN1+residual+BN2 elementwise --------------
__global__ __launch_bounds__(256) void k_final(
    const int* __restrict__ flag,
    const u16* __restrict__ t,
    const u16* __restrict__ feats_raw, const u16* __restrict__ feats_c,
    const u16* __restrict__ g1_raw, const u16* __restrict__ g2_raw,
    const u16* __restrict__ be2_raw, const u16* __restrict__ pc,
    const float* __restrict__ stats,
    void* __restrict__ out)
{
    const bool f32 = (*flag != 0);
    const u16* __restrict__ F   = f32 ? feats_c    : feats_raw;
    const u16* __restrict__ g1  = f32 ? pc + 33024 : g1_raw;
    const u16* __restrict__ g2  = f32 ? pc + 33152 : g2_raw;
    const u16* __restrict__ be2 = f32 ? pc + 33280 : be2_raw;

    __shared__ float sA[DD], sB[DD], sG[DD];
    if (threadIdx.x < DD) {
        const int c = threadIdx.x;
        const float invN = 1.0f / (float)NN;
        const float St  = stats[c],          Stt = stats[DD + c];
        const float Sf  = stats[2 * DD + c], Sff = stats[3 * DD + c];
        const float Stf = stats[4 * DD + c];
        const float mu1  = St * invN;
        const float vart = fmaxf(Stt * invN - mu1 * mu1, 0.f);
        const float muf  = Sf * invN;
        const float varf = fmaxf(Sff * invN - muf * muf, 0.f);
        const float cov  = Stf * invN - mu1 * muf;
        const float r1   = rsqrtf(vart + EPSV);
        const float a1   = bf2f(g1[c]) * r1;
        const float var2 = fmaxf(a1 * a1 * vart + 2.f * a1 * cov + varf, 0.f);
        const float r2   = rsqrtf(var2 + EPSV);
        const float g2r2 = bf2f(g2[c]) * r2;
        sA[c] = g2r2 * a1;
        sB[c] = g2r2;
        sG[c] = bf2f(be2[c]) - g2r2 * (a1 * mu1 + muf);
    }
    __syncthreads();

    float* outf = (float*)out;
    u16*   outb = (u16*)out;
    const size_t P = (size_t)NN * (DD / 2);
    for (size_t i = (size_t)blockIdx.x * blockDim.x + threadIdx.x; i < P;
         i += (size_t)gridDim.x * blockDim.x) {
        const int c = ((int)(i & 63)) * 2;
        const unsigned int tv = *(const unsigned int*)(t + 2 * i);
        const unsigned int fv = *(const unsigned int*)(F + 2 * i);
        const float o0 = sA[c]     * bf2f((u16)(tv & 0xFFFFu))
                       + sB[c]     * bf2f((u16)(fv & 0xFFFFu)) + sG[c];
        const float o1 = sA[c + 1] * bf2f((u16)(tv >> 16))
                       + sB[c + 1] * bf2f((u16)(fv >> 16)) + sG[c + 1];
        if (f32) {
            float2 o; o.x = o0; o.y = o1;
            *(float2*)(outf + 2 * i) = o;
        } else {
            const unsigned int ov = (unsigned int)f2bf(o0) | ((unsigned int)f2bf(o1) << 16);
            *(unsigned int*)(outb + 2 * i) = ov;
        }
    }
}

extern "C" void kernel_launch(void* const* d_in, const int* in_sizes, int n_in,
                              void* d_out, int out_size, void* d_ws, size_t ws_size,
                              hipStream_t stream) {
    const u16* feats = (const u16*)d_in[0];
    const u16* Wg    = (const u16*)d_in[1];
    const u16* bg    = (const u16*)d_in[2];
    const u16* Wr    = (const u16*)d_in[3];
    const u16* br    = (const u16*)d_in[4];
    const u16* g1    = (const u16*)d_in[5];
    // d_in[6] = be1: cancels algebraically, unused
    const u16* g2    = (const u16*)d_in[7];
    const u16* be2   = (const u16*)d_in[8];
    const int* src = (const int*)d_in[9];
    const int* dst = (const int*)d_in[10];

    char* ws = (char*)d_ws;
    u16*          aggb    = (u16*)  ws;
    u16*          t       = (u16*)  (ws + 25600000);
    u16*          feats_c = (u16*)  (ws + 51200000);
    u16*          pc      = (u16*)  (ws + 76800000);
    float*        stats   = (float*)(ws + 76866816);
    int*          flag    = (int*)  (ws + 76869376);
    int*          cnt     = (int*)  (ws + 76869632);
    int*          off     = (int*)  (ws + 76894656);
    int*          cursor  = (int*)  (ws + 76919684);
    int*          row_st  = (int*)  (ws + 76944708);
    unsigned int* arena   = (unsigned int*)(ws + 77344712);

    hipMemsetAsync(cnt,   0, NSEG * sizeof(int), stream);
    hipMemsetAsync(stats, 0, 5 * DD * sizeof(float), stream);

    k_detect<<<1, 256, 0, stream>>>((const float*)d_in[0], flag);
    k_convert_feats<<<1024, 256, 0, stream>>>(flag, (const float*)d_in[0], feats_c);
    k_convert_params<<<131, 256, 0, stream>>>(flag,
        (const float*)d_in[1], (const float*)d_in[3], (const float*)d_in[2],
        (const float*)d_in[4], (const float*)d_in[5], (const float*)d_in[7],
        (const float*)d_in[8], pc);

    k_hist2  <<<256, 256, 0, stream>>>(dst, cnt);
    k_scanseg<<<1, 1024, 0, stream>>>(cnt, off, cursor);
    k_bin    <<<256, 256, 0, stream>>>(src, dst, cursor, arena);
    k_winsort<<<NB, 256, 0, stream>>>(arena, off, row_st);

    k_gather<<<2048, 256, 0, stream>>>(flag, feats, feats_c, (const int*)arena, row_st, aggb);
    k_gemm  <<<1024, 256, 0, stream>>>(flag, aggb, feats, feats_c, Wg, bg, Wr, br, pc, t);
    k_stats <<<784,  256, 0, stream>>>(flag, t, feats, feats_c, stats);
    k_final <<<2048, 256, 0, stream>>>(flag, t, feats, feats_c, g1, g2, be2, pc, stats, d_out);
}